// Round 1
// baseline (528.118 us; speedup 1.0000x reference)
//
#include <hip/hip_runtime.h>
#include <math.h>

#define BB 32
#define TT 256
#define ZDIM 32

__device__ __forceinline__ float softplus_f(float v) {
    // jax.nn.softplus = max(x,0) + log1p(exp(-|x|))
    return fmaxf(v, 0.0f) + log1pf(expf(-fabsf(v)));
}

// Generic tiled 1D conv (K=3, SAME). Output tile: OTILE x 64 (o x t), 256 threads,
// each thread computes OPT o x 4 t outputs. Input channels staged in chunks of 32.
template<int CIN, int COUT, int OTILE, bool RELU, bool IS_STATS>
__global__ __launch_bounds__(256)
void conv_kernel(const float* __restrict__ x, const float* __restrict__ W,
                 const float* __restrict__ bias, float* __restrict__ y,
                 float* __restrict__ out_mu, float* __restrict__ dd,
                 float* __restrict__ ss)
{
    constexpr int CT   = 32;          // input-channel chunk
    constexpr int TTIL = 64;          // t tile
    constexpr int OPT  = OTILE / 16;  // o per thread
    constexpr int XST  = 68;          // padded xs stride (16B-aligned rows)

    __shared__ float xs[CT][XST];
    __shared__ float ws[CT][3][OTILE];

    const int b  = blockIdx.x;
    const int o0 = blockIdx.y * OTILE;
    const int t0 = blockIdx.z * TTIL;

    const int tid = threadIdx.x;
    const int tg  = tid & 15;   // t group (16 groups of 4)
    const int og  = tid >> 4;   // o group (16 groups of OPT)
    const int tb  = tg * 4;
    const int ob  = og * OPT;

    float acc[OPT][4];
    #pragma unroll
    for (int m = 0; m < OPT; ++m) {
        float bv = bias[o0 + ob + m];
        #pragma unroll
        for (int j = 0; j < 4; ++j) acc[m][j] = bv;
    }

    for (int c0 = 0; c0 < CIN; c0 += CT) {
        // stage x tile (with halo, zero pad at sequence edges) — coalesced along t
        for (int idx = tid; idx < CT * 66; idx += 256) {
            int ci = idx / 66;
            int p  = idx - ci * 66;
            int t  = t0 - 1 + p;
            float v = 0.0f;
            if (t >= 0 && t < TT) v = x[(b * CIN + c0 + ci) * TT + t];
            xs[ci][p] = v;
        }
        // stage weights as ws[ci][k][o] — coalesced reads of W[o][ci][k]
        for (int idx = tid; idx < OTILE * CT * 3; idx += 256) {
            int o  = idx / (CT * 3);
            int r2 = idx - o * (CT * 3);
            int ci = r2 / 3;
            int k  = r2 - ci * 3;
            ws[ci][k][o] = W[(o0 + o) * CIN * 3 + (c0 + ci) * 3 + k];
        }
        __syncthreads();

        #pragma unroll 8
        for (int ci = 0; ci < CT; ++ci) {
            float xv[6];
            #pragma unroll
            for (int p = 0; p < 6; ++p) xv[p] = xs[ci][tb + p];
            #pragma unroll
            for (int k = 0; k < 3; ++k) {
                float wv[OPT];
                #pragma unroll
                for (int m = 0; m < OPT; ++m) wv[m] = ws[ci][k][ob + m];
                #pragma unroll
                for (int m = 0; m < OPT; ++m)
                    #pragma unroll
                    for (int j = 0; j < 4; ++j)
                        acc[m][j] = fmaf(wv[m], xv[k + j], acc[m][j]);
            }
        }
        __syncthreads();
    }

    if (!IS_STATS) {
        #pragma unroll
        for (int m = 0; m < OPT; ++m) {
            int o = o0 + ob + m;
            float4 v = {acc[m][0], acc[m][1], acc[m][2], acc[m][3]};
            if (RELU) {
                v.x = fmaxf(v.x, 0.f); v.y = fmaxf(v.y, 0.f);
                v.z = fmaxf(v.z, 0.f); v.w = fmaxf(v.w, 0.f);
            }
            *(float4*)&y[(b * COUT + o) * TT + t0 + tb] = v;
        }
    } else {
        // stats layer: o<32 -> mu, even o>=32 -> d = softplus+1, odd -> s = softplus
        #pragma unroll
        for (int m = 0; m < OPT; ++m) {
            int o = o0 + ob + m;
            int tbase = t0 + tb;
            if (o < ZDIM) {
                float4 v = {acc[m][0], acc[m][1], acc[m][2], acc[m][3]};
                *(float4*)&out_mu[(b * ZDIM + o) * TT + tbase] = v;
            } else {
                int oc = o - ZDIM;
                int z  = oc >> 1;
                float4 v;
                v.x = softplus_f(acc[m][0]); v.y = softplus_f(acc[m][1]);
                v.z = softplus_f(acc[m][2]); v.w = softplus_f(acc[m][3]);
                if ((oc & 1) == 0) {
                    v.x += 1.f; v.y += 1.f; v.z += 1.f; v.w += 1.f;
                    *(float4*)&dd[(b * ZDIM + z) * TT + tbase] = v;
                } else {
                    *(float4*)&ss[(b * ZDIM + z) * TT + tbase] = v;
                }
            }
        }
    }
}

// scale_tril[r,c] = invd[r] * prod_{k=c}^{r-1} t_k   (t_k = -s_k/d_k), 0 above diag.
// One wave per (b,z) matrix; lane handles 4 consecutive columns; per-row float4
// stores are fully coalesced (1 KB per wave per row). HBM-write-bound.
__global__ __launch_bounds__(64)
void tril_kernel(const float* __restrict__ dd, const float* __restrict__ ss,
                 float* __restrict__ out)
{
    __shared__ float invd[TT];
    __shared__ float tt[TT];

    const int bz  = blockIdx.x;      // 0..1023
    const int tid = threadIdx.x;     // 0..63
    const int c0  = tid * 4;

    float4 dv = *(const float4*)&dd[bz * TT + c0];
    float4 sv = *(const float4*)&ss[bz * TT + c0];
    float4 iv = {1.0f / dv.x, 1.0f / dv.y, 1.0f / dv.z, 1.0f / dv.w};
    *(float4*)&invd[c0] = iv;
    float4 tv = {-sv.x * iv.x, -sv.y * iv.y, -sv.z * iv.z, -sv.w * iv.w};
    *(float4*)&tt[c0] = tv;
    __syncthreads();

    float p0 = 0.f, p1 = 0.f, p2 = 0.f, p3 = 0.f;
    float* orow = out + (size_t)bz * TT * TT;

    for (int r = 0; r < TT; ++r) {
        float tm = (r > 0) ? tt[r - 1] : 0.0f;
        p0 = (r == c0    ) ? 1.0f : p0 * tm;
        p1 = (r == c0 + 1) ? 1.0f : p1 * tm;
        p2 = (r == c0 + 2) ? 1.0f : p2 * tm;
        p3 = (r == c0 + 3) ? 1.0f : p3 * tm;
        float id = invd[r];
        float4 v = {p0 * id, p1 * id, p2 * id, p3 * id};
        // match reference's isfinite -> 0 replacement (also cleans 0*inf NaNs
        // above the diagonal before they are overwritten logically)
        v.x = isfinite(v.x) ? v.x : 0.0f;
        v.y = isfinite(v.y) ? v.y : 0.0f;
        v.z = isfinite(v.z) ? v.z : 0.0f;
        v.w = isfinite(v.w) ? v.w : 0.0f;
        *(float4*)&orow[r * TT + c0] = v;
    }
}

extern "C" void kernel_launch(void* const* d_in, const int* in_sizes, int n_in,
                              void* d_out, int out_size, void* d_ws, size_t ws_size,
                              hipStream_t stream)
{
    const float* x  = (const float*)d_in[0];
    const float* W0 = (const float*)d_in[1];
    const float* b0 = (const float*)d_in[2];
    const float* W1 = (const float*)d_in[3];
    const float* b1 = (const float*)d_in[4];
    const float* W2 = (const float*)d_in[5];
    const float* b2 = (const float*)d_in[6];

    float* out = (float*)d_out;
    float* mu  = out;                         // (32,32,256)
    float* st  = out + BB * ZDIM * TT;        // (32,32,256,256)

    float* h0 = (float*)d_ws;                 // (32,256,256)
    float* h1 = h0 + BB * 256 * TT;           // (32,256,256)
    float* dd = h1 + BB * 256 * TT;           // (32,32,256)  d = softplus+1
    float* ss = dd + BB * ZDIM * TT;          // (32,32,256)  s = softplus

    // conv1: 64 -> 256, relu
    conv_kernel<64, 256, 64, true, false><<<dim3(BB, 4, 4), 256, 0, stream>>>(
        x, W0, b0, h0, nullptr, nullptr, nullptr);
    // conv2: 256 -> 256, relu
    conv_kernel<256, 256, 64, true, false><<<dim3(BB, 4, 4), 256, 0, stream>>>(
        h0, W1, b1, h1, nullptr, nullptr, nullptr);
    // conv3: 256 -> 96, stats (mu / d / s)
    conv_kernel<256, 96, 96, false, true><<<dim3(BB, 1, 4), 256, 0, stream>>>(
        h1, W2, b2, nullptr, mu, dd, ss);
    // banded inverse-transpose, write-bound
    tril_kernel<<<dim3(BB * ZDIM), 64, 0, stream>>>(dd, ss, st);
}

// Round 3
// 498.510 us; speedup vs baseline: 1.0594x; 1.0594x over previous
//
#include <hip/hip_runtime.h>
#include <math.h>

#define BB 32
#define TT 256
#define ZDIM 32

typedef float vf4 __attribute__((ext_vector_type(4)));  // native vector: works with nontemporal builtin

__device__ __forceinline__ float softplus_f(float v) {
    // jax.nn.softplus = max(x,0) + log1p(exp(-|x|))
    return fmaxf(v, 0.0f) + log1pf(expf(-fabsf(v)));
}

// Generic tiled 1D conv (K=3, SAME). Output tile: OTILE x 64 (o x t), 256 threads,
// each thread computes OPT o x 4 t outputs. Input channels staged in chunks of 32.
// NOTE: unroll kept at 2 — unroll 8 risks pipelined live-set > 256 VGPRs (spills).
template<int CIN, int COUT, int OTILE, bool RELU, bool IS_STATS>
__global__ __launch_bounds__(256)
void conv_kernel(const float* __restrict__ x, const float* __restrict__ W,
                 const float* __restrict__ bias, float* __restrict__ y,
                 float* __restrict__ out_mu, float* __restrict__ dd,
                 float* __restrict__ ss)
{
    constexpr int CT   = 32;          // input-channel chunk
    constexpr int TTIL = 64;          // t tile
    constexpr int OPT  = OTILE / 16;  // o per thread
    constexpr int XST  = 68;          // padded xs stride (16B-aligned rows)

    __shared__ float xs[CT][XST];
    __shared__ float ws[CT][3][OTILE];

    const int b  = blockIdx.x;
    const int o0 = blockIdx.y * OTILE;
    const int t0 = blockIdx.z * TTIL;

    const int tid = threadIdx.x;
    const int tg  = tid & 15;   // t group (16 groups of 4)
    const int og  = tid >> 4;   // o group (16 groups of OPT)
    const int tb  = tg * 4;
    const int ob  = og * OPT;

    float acc[OPT][4];
    #pragma unroll
    for (int m = 0; m < OPT; ++m) {
        float bv = bias[o0 + ob + m];
        #pragma unroll
        for (int j = 0; j < 4; ++j) acc[m][j] = bv;
    }

    for (int c0 = 0; c0 < CIN; c0 += CT) {
        // stage x tile (with halo, zero pad at sequence edges) — coalesced along t
        for (int idx = tid; idx < CT * 66; idx += 256) {
            int ci = idx / 66;
            int p  = idx - ci * 66;
            int t  = t0 - 1 + p;
            float v = 0.0f;
            if (t >= 0 && t < TT) v = x[(b * CIN + c0 + ci) * TT + t];
            xs[ci][p] = v;
        }
        // stage weights as ws[ci][k][o] — coalesced reads of W[o][ci][k]
        for (int idx = tid; idx < OTILE * CT * 3; idx += 256) {
            int o  = idx / (CT * 3);
            int r2 = idx - o * (CT * 3);
            int ci = r2 / 3;
            int k  = r2 - ci * 3;
            ws[ci][k][o] = W[(o0 + o) * CIN * 3 + (c0 + ci) * 3 + k];
        }
        __syncthreads();

        #pragma unroll 2
        for (int ci = 0; ci < CT; ++ci) {
            float xv[6];
            #pragma unroll
            for (int p = 0; p < 6; ++p) xv[p] = xs[ci][tb + p];
            #pragma unroll
            for (int k = 0; k < 3; ++k) {
                float wv[OPT];
                #pragma unroll
                for (int m = 0; m < OPT; ++m) wv[m] = ws[ci][k][ob + m];
                #pragma unroll
                for (int m = 0; m < OPT; ++m)
                    #pragma unroll
                    for (int j = 0; j < 4; ++j)
                        acc[m][j] = fmaf(wv[m], xv[k + j], acc[m][j]);
            }
        }
        __syncthreads();
    }

    if (!IS_STATS) {
        #pragma unroll
        for (int m = 0; m < OPT; ++m) {
            int o = o0 + ob + m;
            float4 v = {acc[m][0], acc[m][1], acc[m][2], acc[m][3]};
            if (RELU) {
                v.x = fmaxf(v.x, 0.f); v.y = fmaxf(v.y, 0.f);
                v.z = fmaxf(v.z, 0.f); v.w = fmaxf(v.w, 0.f);
            }
            *(float4*)&y[(b * COUT + o) * TT + t0 + tb] = v;
        }
    } else {
        // stats layer: o<32 -> mu, even o>=32 -> d = softplus+1, odd -> s = softplus
        #pragma unroll
        for (int m = 0; m < OPT; ++m) {
            int o = o0 + ob + m;
            int tbase = t0 + tb;
            if (o < ZDIM) {
                float4 v = {acc[m][0], acc[m][1], acc[m][2], acc[m][3]};
                *(float4*)&out_mu[(b * ZDIM + o) * TT + tbase] = v;
            } else {
                int oc = o - ZDIM;
                int z  = oc >> 1;
                float4 v;
                v.x = softplus_f(acc[m][0]); v.y = softplus_f(acc[m][1]);
                v.z = softplus_f(acc[m][2]); v.w = softplus_f(acc[m][3]);
                if ((oc & 1) == 0) {
                    v.x += 1.f; v.y += 1.f; v.z += 1.f; v.w += 1.f;
                    *(float4*)&dd[(b * ZDIM + z) * TT + tbase] = v;
                } else {
                    *(float4*)&ss[(b * ZDIM + z) * TT + tbase] = v;
                }
            }
        }
    }
}

// scale_tril[r,c] = invd[r] * prod_{k=c}^{r-1} t_k   (t_k = -s_k/d_k), 0 above diag.
// One wave per (b,z) matrix; lane handles 4 consecutive columns; per-row float4
// stores are fully coalesced (1 KB per wave per row). HBM-write-bound.
// Non-temporal stores: the 268 MB output is streamed, never re-read.
__global__ __launch_bounds__(64)
void tril_kernel(const float* __restrict__ dd, const float* __restrict__ ss,
                 float* __restrict__ out)
{
    __shared__ float invd[TT];
    __shared__ float tt[TT];

    const int bz  = blockIdx.x;      // 0..1023
    const int tid = threadIdx.x;     // 0..63
    const int c0  = tid * 4;

    float4 dv = *(const float4*)&dd[bz * TT + c0];
    float4 sv = *(const float4*)&ss[bz * TT + c0];
    float4 iv = {1.0f / dv.x, 1.0f / dv.y, 1.0f / dv.z, 1.0f / dv.w};
    *(float4*)&invd[c0] = iv;
    float4 tv = {-sv.x * iv.x, -sv.y * iv.y, -sv.z * iv.z, -sv.w * iv.w};
    *(float4*)&tt[c0] = tv;
    __syncthreads();

    float p0 = 0.f, p1 = 0.f, p2 = 0.f, p3 = 0.f;
    float* orow = out + (size_t)bz * TT * TT + c0;

    #pragma unroll 2
    for (int r = 0; r < TT; ++r) {
        float tm = (r > 0) ? tt[r - 1] : 0.0f;
        p0 = (r == c0    ) ? 1.0f : p0 * tm;
        p1 = (r == c0 + 1) ? 1.0f : p1 * tm;
        p2 = (r == c0 + 2) ? 1.0f : p2 * tm;
        p3 = (r == c0 + 3) ? 1.0f : p3 * tm;
        float id = invd[r];
        vf4 v;
        v.x = p0 * id; v.y = p1 * id; v.z = p2 * id; v.w = p3 * id;
        // match reference's isfinite -> 0 replacement
        v.x = isfinite(v.x) ? v.x : 0.0f;
        v.y = isfinite(v.y) ? v.y : 0.0f;
        v.z = isfinite(v.z) ? v.z : 0.0f;
        v.w = isfinite(v.w) ? v.w : 0.0f;
        __builtin_nontemporal_store(v, (vf4*)orow);
        orow += TT;
    }
}

extern "C" void kernel_launch(void* const* d_in, const int* in_sizes, int n_in,
                              void* d_out, int out_size, void* d_ws, size_t ws_size,
                              hipStream_t stream)
{
    const float* x  = (const float*)d_in[0];
    const float* W0 = (const float*)d_in[1];
    const float* b0 = (const float*)d_in[2];
    const float* W1 = (const float*)d_in[3];
    const float* b1 = (const float*)d_in[4];
    const float* W2 = (const float*)d_in[5];
    const float* b2 = (const float*)d_in[6];

    float* out = (float*)d_out;
    float* mu  = out;                         // (32,32,256)
    float* st  = out + BB * ZDIM * TT;        // (32,32,256,256)

    float* h0 = (float*)d_ws;                 // (32,256,256)
    float* h1 = h0 + BB * 256 * TT;           // (32,256,256)
    float* dd = h1 + BB * 256 * TT;           // (32,32,256)  d = softplus+1
    float* ss = dd + BB * ZDIM * TT;          // (32,32,256)  s = softplus

    // conv1: 64 -> 256, relu
    conv_kernel<64, 256, 64, true, false><<<dim3(BB, 4, 4), 256, 0, stream>>>(
        x, W0, b0, h0, nullptr, nullptr, nullptr);
    // conv2: 256 -> 256, relu
    conv_kernel<256, 256, 64, true, false><<<dim3(BB, 4, 4), 256, 0, stream>>>(
        h0, W1, b1, h1, nullptr, nullptr, nullptr);
    // conv3: 256 -> 96, stats (mu / d / s) — OTILE=32 -> 384 blocks (was 128)
    conv_kernel<256, 96, 32, false, true><<<dim3(BB, 3, 4), 256, 0, stream>>>(
        h1, W2, b2, nullptr, mu, dd, ss);
    // banded inverse-transpose, write-bound
    tril_kernel<<<dim3(BB * ZDIM), 64, 0, stream>>>(dd, ss, st);
}

// Round 5
// 493.409 us; speedup vs baseline: 1.0703x; 1.0103x over previous
//
#include <hip/hip_runtime.h>
#include <math.h>

#define BB 32
#define TT 256
#define ZDIM 32

typedef float vf4 __attribute__((ext_vector_type(4)));
typedef float vf2 __attribute__((ext_vector_type(2)));

__device__ __forceinline__ float softplus_f(float v) {
    // jax.nn.softplus = max(x,0) + log1p(exp(-|x|))
    return fmaxf(v, 0.0f) + log1pf(expf(-fabsf(v)));
}

// Generic tiled 1D conv (K=3, SAME). Output tile: OTILE x 64 (o x t), 256 threads,
// each thread computes OPT o x 4 t outputs. Input channels staged in chunks of 32.
// LDS reads are explicit b128/b64 vectors: 5 LDS instrs per ci (was 18 scalar) vs
// 48 FMAs -> FMA-bound inner loop. xs row stride 68 floats = 272 B = 17*16 B, so
// every row is 16B-aligned; tb/ob are multiples of 4 floats.
template<int CIN, int COUT, int OTILE, bool RELU, bool IS_STATS>
__global__ __launch_bounds__(256)
void conv_kernel(const float* __restrict__ x, const float* __restrict__ W,
                 const float* __restrict__ bias, float* __restrict__ y,
                 float* __restrict__ out_mu, float* __restrict__ dd,
                 float* __restrict__ ss)
{
    constexpr int CT   = 32;          // input-channel chunk
    constexpr int TTIL = 64;          // t tile
    constexpr int OPT  = OTILE / 16;  // o per thread (4 or 2)
    constexpr int XST  = 68;          // padded xs stride (16B-aligned rows)
    static_assert(OPT == 4 || OPT == 2, "OPT must be 2 or 4");

    __shared__ float xs[CT][XST];
    __shared__ float ws[CT][3][OTILE];

    const int b  = blockIdx.x;
    const int o0 = blockIdx.y * OTILE;
    const int t0 = blockIdx.z * TTIL;

    const int tid = threadIdx.x;
    const int tg  = tid & 15;   // t group (16 groups of 4)
    const int og  = tid >> 4;   // o group (16 groups of OPT)
    const int tb  = tg * 4;
    const int ob  = og * OPT;

    float acc[OPT][4];
    #pragma unroll
    for (int m = 0; m < OPT; ++m) {
        float bv = bias[o0 + ob + m];
        #pragma unroll
        for (int j = 0; j < 4; ++j) acc[m][j] = bv;
    }

    for (int c0 = 0; c0 < CIN; c0 += CT) {
        // stage x tile (with halo, zero pad at sequence edges) — coalesced along t
        for (int idx = tid; idx < CT * 66; idx += 256) {
            int ci = idx / 66;
            int p  = idx - ci * 66;
            int t  = t0 - 1 + p;
            float v = 0.0f;
            if (t >= 0 && t < TT) v = x[(b * CIN + c0 + ci) * TT + t];
            xs[ci][p] = v;
        }
        // stage weights as ws[ci][k][o] — coalesced reads of W[o][ci][k]
        for (int idx = tid; idx < OTILE * CT * 3; idx += 256) {
            int o  = idx / (CT * 3);
            int r2 = idx - o * (CT * 3);
            int ci = r2 / 3;
            int k  = r2 - ci * 3;
            ws[ci][k][o] = W[(o0 + o) * CIN * 3 + (c0 + ci) * 3 + k];
        }
        __syncthreads();

        #pragma unroll 4
        for (int ci = 0; ci < CT; ++ci) {
            vf4 xa = *(const vf4*)&xs[ci][tb];       // xs[ci][tb..tb+3]
            vf2 xb = *(const vf2*)&xs[ci][tb + 4];   // xs[ci][tb+4..tb+5]
            float xv[6] = {xa.x, xa.y, xa.z, xa.w, xb.x, xb.y};
            #pragma unroll
            for (int k = 0; k < 3; ++k) {
                float wv[OPT];
                if constexpr (OPT == 4) {
                    vf4 w = *(const vf4*)&ws[ci][k][ob];
                    wv[0] = w.x; wv[1] = w.y; wv[2] = w.z; wv[3] = w.w;
                } else {
                    vf2 w = *(const vf2*)&ws[ci][k][ob];
                    wv[0] = w.x; wv[1] = w.y;
                }
                #pragma unroll
                for (int m = 0; m < OPT; ++m)
                    #pragma unroll
                    for (int j = 0; j < 4; ++j)
                        acc[m][j] = fmaf(wv[m], xv[k + j], acc[m][j]);
            }
        }
        __syncthreads();
    }

    if (!IS_STATS) {
        #pragma unroll
        for (int m = 0; m < OPT; ++m) {
            int o = o0 + ob + m;
            float4 v = {acc[m][0], acc[m][1], acc[m][2], acc[m][3]};
            if (RELU) {
                v.x = fmaxf(v.x, 0.f); v.y = fmaxf(v.y, 0.f);
                v.z = fmaxf(v.z, 0.f); v.w = fmaxf(v.w, 0.f);
            }
            *(float4*)&y[(b * COUT + o) * TT + t0 + tb] = v;
        }
    } else {
        // stats layer: o<32 -> mu, even o>=32 -> d = softplus+1, odd -> s = softplus
        #pragma unroll
        for (int m = 0; m < OPT; ++m) {
            int o = o0 + ob + m;
            int tbase = t0 + tb;
            if (o < ZDIM) {
                float4 v = {acc[m][0], acc[m][1], acc[m][2], acc[m][3]};
                *(float4*)&out_mu[(b * ZDIM + o) * TT + tbase] = v;
            } else {
                int oc = o - ZDIM;
                int z  = oc >> 1;
                float4 v;
                v.x = softplus_f(acc[m][0]); v.y = softplus_f(acc[m][1]);
                v.z = softplus_f(acc[m][2]); v.w = softplus_f(acc[m][3]);
                if ((oc & 1) == 0) {
                    v.x += 1.f; v.y += 1.f; v.z += 1.f; v.w += 1.f;
                    *(float4*)&dd[(b * ZDIM + z) * TT + tbase] = v;
                } else {
                    *(float4*)&ss[(b * ZDIM + z) * TT + tbase] = v;
                }
            }
        }
    }
}

// scale_tril[r,c] = invd[r] * prod_{k=c}^{r-1} t_k   (t_k = -s_k/d_k), 0 above diag.
// Grid (bz, band): each wave handles 64 rows of one (b,z) matrix.
// The row loop at row r multiplies by tt[r-1], so the seed entering r0 must be
// prod_{k=c}^{r0-2} t_k (the first in-band iteration supplies t_{r0-1}).
// Same ascending multiply order as the single-wave version -> bit-identical.
// 4096 waves -> ~16 waves/CU for store-latency hiding. Non-temporal float4
// stores: 268 MB streamed, never re-read.
__global__ __launch_bounds__(64)
void tril_kernel(const float* __restrict__ dd, const float* __restrict__ ss,
                 float* __restrict__ out)
{
    __shared__ float invd[TT];
    __shared__ float tt[TT];

    const int bz  = blockIdx.x;      // 0..1023
    const int r0  = blockIdx.y * 64; // band start row
    const int tid = threadIdx.x;     // 0..63
    const int c0  = tid * 4;

    float4 dv = *(const float4*)&dd[bz * TT + c0];
    float4 sv = *(const float4*)&ss[bz * TT + c0];
    float4 iv = {1.0f / dv.x, 1.0f / dv.y, 1.0f / dv.z, 1.0f / dv.w};
    *(float4*)&invd[c0] = iv;
    float4 tv = {-sv.x * iv.x, -sv.y * iv.y, -sv.z * iv.z, -sv.w * iv.w};
    *(float4*)&tt[c0] = tv;
    __syncthreads();

    // seed: p_j = prod_{k=c_j}^{r0-2} t_k (ascending; first loop iter adds t_{r0-1})
    float p0 = 1.f, p1 = 1.f, p2 = 1.f, p3 = 1.f;
    for (int k = 0; k < r0 - 1; ++k) {
        float tm = tt[k];
        p0 = (k >= c0    ) ? p0 * tm : p0;
        p1 = (k >= c0 + 1) ? p1 * tm : p1;
        p2 = (k >= c0 + 2) ? p2 * tm : p2;
        p3 = (k >= c0 + 3) ? p3 * tm : p3;
    }
    // columns at/after the band start haven't hit their diagonal yet
    p0 = (c0     < r0) ? p0 : 0.f;
    p1 = (c0 + 1 < r0) ? p1 : 0.f;
    p2 = (c0 + 2 < r0) ? p2 : 0.f;
    p3 = (c0 + 3 < r0) ? p3 : 0.f;

    float* orow = out + (size_t)bz * TT * TT + (size_t)r0 * TT + c0;

    #pragma unroll 2
    for (int r = r0; r < r0 + 64; ++r) {
        float tm = (r > 0) ? tt[r - 1] : 0.0f;
        p0 = (r == c0    ) ? 1.0f : p0 * tm;
        p1 = (r == c0 + 1) ? 1.0f : p1 * tm;
        p2 = (r == c0 + 2) ? 1.0f : p2 * tm;
        p3 = (r == c0 + 3) ? 1.0f : p3 * tm;
        float id = invd[r];
        vf4 v;
        v.x = p0 * id; v.y = p1 * id; v.z = p2 * id; v.w = p3 * id;
        // match reference's isfinite -> 0 replacement
        v.x = isfinite(v.x) ? v.x : 0.0f;
        v.y = isfinite(v.y) ? v.y : 0.0f;
        v.z = isfinite(v.z) ? v.z : 0.0f;
        v.w = isfinite(v.w) ? v.w : 0.0f;
        __builtin_nontemporal_store(v, (vf4*)orow);
        orow += TT;
    }
}

extern "C" void kernel_launch(void* const* d_in, const int* in_sizes, int n_in,
                              void* d_out, int out_size, void* d_ws, size_t ws_size,
                              hipStream_t stream)
{
    const float* x  = (const float*)d_in[0];
    const float* W0 = (const float*)d_in[1];
    const float* b0 = (const float*)d_in[2];
    const float* W1 = (const float*)d_in[3];
    const float* b1 = (const float*)d_in[4];
    const float* W2 = (const float*)d_in[5];
    const float* b2 = (const float*)d_in[6];

    float* out = (float*)d_out;
    float* mu  = out;                         // (32,32,256)
    float* st  = out + BB * ZDIM * TT;        // (32,32,256,256)

    float* h0 = (float*)d_ws;                 // (32,256,256)
    float* h1 = h0 + BB * 256 * TT;           // (32,256,256)
    float* dd = h1 + BB * 256 * TT;           // (32,32,256)  d = softplus+1
    float* ss = dd + BB * ZDIM * TT;          // (32,32,256)  s = softplus

    // conv1: 64 -> 256, relu
    conv_kernel<64, 256, 64, true, false><<<dim3(BB, 4, 4), 256, 0, stream>>>(
        x, W0, b0, h0, nullptr, nullptr, nullptr);
    // conv2: 256 -> 256, relu
    conv_kernel<256, 256, 64, true, false><<<dim3(BB, 4, 4), 256, 0, stream>>>(
        h0, W1, b1, h1, nullptr, nullptr, nullptr);
    // conv3: 256 -> 96, stats (mu / d / s)
    conv_kernel<256, 96, 32, false, true><<<dim3(BB, 3, 4), 256, 0, stream>>>(
        h1, W2, b2, nullptr, mu, dd, ss);
    // banded inverse-transpose, write-bound; 4 row-bands per (b,z)
    tril_kernel<<<dim3(BB * ZDIM, 4), 64, 0, stream>>>(dd, ss, st);
}

// Round 6
// 452.341 us; speedup vs baseline: 1.1675x; 1.0908x over previous
//
#include <hip/hip_runtime.h>
#include <hip/hip_bf16.h>
#include <math.h>

#define BB 32
#define TT 256
#define ZDIM 32

typedef float vf4 __attribute__((ext_vector_type(4)));
typedef float vf2 __attribute__((ext_vector_type(2)));
typedef short short8 __attribute__((ext_vector_type(8)));
typedef float f32x4 __attribute__((ext_vector_type(4)));

__device__ __forceinline__ float softplus_f(float v) {
    return fmaxf(v, 0.0f) + log1pf(expf(-fabsf(v)));
}

__device__ __forceinline__ short f2bf(float f) {
    __hip_bfloat16 h = __float2bfloat16(f);
    return *reinterpret_cast<short*>(&h);
}

// ---------------- fp32 conv (used for conv1 and conv3) ----------------
template<int CIN, int COUT, int OTILE, bool RELU, bool IS_STATS>
__global__ __launch_bounds__(256)
void conv_kernel(const float* __restrict__ x, const float* __restrict__ W,
                 const float* __restrict__ bias, float* __restrict__ y,
                 float* __restrict__ out_mu, float* __restrict__ dd,
                 float* __restrict__ ss)
{
    constexpr int CT   = 32;
    constexpr int TTIL = 64;
    constexpr int OPT  = OTILE / 16;
    constexpr int XST  = 68;
    static_assert(OPT == 4 || OPT == 2, "OPT must be 2 or 4");

    __shared__ float xs[CT][XST];
    __shared__ float ws[CT][3][OTILE];

    const int b  = blockIdx.x;
    const int o0 = blockIdx.y * OTILE;
    const int t0 = blockIdx.z * TTIL;

    const int tid = threadIdx.x;
    const int tg  = tid & 15;
    const int og  = tid >> 4;
    const int tb  = tg * 4;
    const int ob  = og * OPT;

    float acc[OPT][4];
    #pragma unroll
    for (int m = 0; m < OPT; ++m) {
        float bv = bias[o0 + ob + m];
        #pragma unroll
        for (int j = 0; j < 4; ++j) acc[m][j] = bv;
    }

    for (int c0 = 0; c0 < CIN; c0 += CT) {
        for (int idx = tid; idx < CT * 66; idx += 256) {
            int ci = idx / 66;
            int p  = idx - ci * 66;
            int t  = t0 - 1 + p;
            float v = 0.0f;
            if (t >= 0 && t < TT) v = x[(b * CIN + c0 + ci) * TT + t];
            xs[ci][p] = v;
        }
        for (int idx = tid; idx < OTILE * CT * 3; idx += 256) {
            int o  = idx / (CT * 3);
            int r2 = idx - o * (CT * 3);
            int ci = r2 / 3;
            int k  = r2 - ci * 3;
            ws[ci][k][o] = W[(o0 + o) * CIN * 3 + (c0 + ci) * 3 + k];
        }
        __syncthreads();

        #pragma unroll 4
        for (int ci = 0; ci < CT; ++ci) {
            vf4 xa = *(const vf4*)&xs[ci][tb];
            vf2 xb = *(const vf2*)&xs[ci][tb + 4];
            float xv[6] = {xa.x, xa.y, xa.z, xa.w, xb.x, xb.y};
            #pragma unroll
            for (int k = 0; k < 3; ++k) {
                float wv[OPT];
                if constexpr (OPT == 4) {
                    vf4 w = *(const vf4*)&ws[ci][k][ob];
                    wv[0] = w.x; wv[1] = w.y; wv[2] = w.z; wv[3] = w.w;
                } else {
                    vf2 w = *(const vf2*)&ws[ci][k][ob];
                    wv[0] = w.x; wv[1] = w.y;
                }
                #pragma unroll
                for (int m = 0; m < OPT; ++m)
                    #pragma unroll
                    for (int j = 0; j < 4; ++j)
                        acc[m][j] = fmaf(wv[m], xv[k + j], acc[m][j]);
            }
        }
        __syncthreads();
    }

    if (!IS_STATS) {
        #pragma unroll
        for (int m = 0; m < OPT; ++m) {
            int o = o0 + ob + m;
            float4 v = {acc[m][0], acc[m][1], acc[m][2], acc[m][3]};
            if (RELU) {
                v.x = fmaxf(v.x, 0.f); v.y = fmaxf(v.y, 0.f);
                v.z = fmaxf(v.z, 0.f); v.w = fmaxf(v.w, 0.f);
            }
            *(float4*)&y[(b * COUT + o) * TT + t0 + tb] = v;
        }
    } else {
        #pragma unroll
        for (int m = 0; m < OPT; ++m) {
            int o = o0 + ob + m;
            int tbase = t0 + tb;
            if (o < ZDIM) {
                float4 v = {acc[m][0], acc[m][1], acc[m][2], acc[m][3]};
                *(float4*)&out_mu[(b * ZDIM + o) * TT + tbase] = v;
            } else {
                int oc = o - ZDIM;
                int z  = oc >> 1;
                float4 v;
                v.x = softplus_f(acc[m][0]); v.y = softplus_f(acc[m][1]);
                v.z = softplus_f(acc[m][2]); v.w = softplus_f(acc[m][3]);
                if ((oc & 1) == 0) {
                    v.x += 1.f; v.y += 1.f; v.z += 1.f; v.w += 1.f;
                    *(float4*)&dd[(b * ZDIM + z) * TT + tbase] = v;
                } else {
                    *(float4*)&ss[(b * ZDIM + z) * TT + tbase] = v;
                }
            }
        }
    }
}

// ---------------- bf16 MFMA conv2 (256 -> 256, relu) ----------------
// Conv as 3 shifted GEMMs: y[o][t] += sum_ci W[o][ci][k] * x[ci][t+k-1].
// Block = 4 waves, output 64o x 64t; wave computes a 16o x 64t strip via
// 16x16x32 bf16 MFMA. LDS: x-tile transposed to [t+halo][ci] (so the k-shift
// is a free row offset) and W as [k][o][ci]; both bf16 with ci-rows padded to
// 72 (144 B = 36 dwords) to break the 32-dword bank stride.
// Layouts (m89-verified): A[m=lane&15][ci=quad*8+j], B[ci=quad*8+j][n=lane&15],
// C row = quad*4+reg, col = lane&15.
__global__ __launch_bounds__(256)
void conv2_mfma(const float* __restrict__ x,   // h0 [B][256][256]
                const float* __restrict__ W,   // [256][256][3]
                const float* __restrict__ bias,
                float* __restrict__ y)         // h1 [B][256][256]
{
    constexpr int CIN = 256, COUT = 256;
    constexpr int CT  = 64;    // ci chunk
    constexpr int PAD = 72;    // padded ci row length

    __shared__ short xsb[66][PAD];       // [p = t-halo][ci]
    __shared__ short wsb[3][64][PAD];    // [k][o][ci]

    const int b    = blockIdx.x;
    const int o0   = blockIdx.y * 64;
    const int t0   = blockIdx.z * 64;
    const int tid  = threadIdx.x;
    const int wv   = tid >> 6;
    const int lane = tid & 63;
    const int l15  = lane & 15;
    const int quad = lane >> 4;

    f32x4 acc[4];
    {
        f32x4 bv;
        #pragma unroll
        for (int r = 0; r < 4; ++r) bv[r] = bias[o0 + wv * 16 + quad * 4 + r];
        #pragma unroll
        for (int nt = 0; nt < 4; ++nt) acc[nt] = bv;
    }

    for (int c0 = 0; c0 < CIN; c0 += CT) {
        if (c0) __syncthreads();
        // stage x tile: coalesced global read along t, bf16 convert,
        // transposed LDS write ([p][ci]).
        for (int idx = tid; idx < CT * 66; idx += 256) {
            int ci = idx / 66;
            int p  = idx - ci * 66;
            int t  = t0 - 1 + p;
            float v = (t >= 0 && t < TT) ? x[(b * CIN + c0 + ci) * TT + t] : 0.f;
            xsb[p][ci] = f2bf(v);
        }
        // stage weights: W[(o0+o)*768 + (c0+ci)*3 + k] — 192 consecutive per o.
        for (int idx = tid; idx < 64 * 192; idx += 256) {
            int o = idx / 192;
            int r = idx - o * 192;
            int ci = r / 3;
            int k  = r - ci * 3;
            wsb[k][o][ci] = f2bf(W[(o0 + o) * (CIN * 3) + (c0 + ci) * 3 + k]);
        }
        __syncthreads();

        #pragma unroll
        for (int ks = 0; ks < 3; ++ks) {
            #pragma unroll
            for (int kc = 0; kc < CT; kc += 32) {
                short8 af = *(const short8*)&wsb[ks][wv * 16 + l15][kc + quad * 8];
                #pragma unroll
                for (int nt = 0; nt < 4; ++nt) {
                    short8 bf = *(const short8*)&xsb[nt * 16 + l15 + ks][kc + quad * 8];
                    acc[nt] = __builtin_amdgcn_mfma_f32_16x16x32_bf16(af, bf, acc[nt], 0, 0, 0);
                }
            }
        }
    }

    // epilogue: relu + store (16 lanes consecutive in t -> 64 B segments)
    #pragma unroll
    for (int nt = 0; nt < 4; ++nt) {
        int t = t0 + nt * 16 + l15;
        #pragma unroll
        for (int r = 0; r < 4; ++r) {
            int o = o0 + wv * 16 + quad * 4 + r;
            y[(b * COUT + o) * TT + t] = fmaxf(acc[nt][r], 0.f);
        }
    }
}

// ---------------- banded inverse-transpose ----------------
__global__ __launch_bounds__(64)
void tril_kernel(const float* __restrict__ dd, const float* __restrict__ ss,
                 float* __restrict__ out)
{
    __shared__ float invd[TT];
    __shared__ float tt[TT];

    const int bz  = blockIdx.x;
    const int r0  = blockIdx.y * 64;
    const int tid = threadIdx.x;
    const int c0  = tid * 4;

    float4 dv = *(const float4*)&dd[bz * TT + c0];
    float4 sv = *(const float4*)&ss[bz * TT + c0];
    float4 iv = {1.0f / dv.x, 1.0f / dv.y, 1.0f / dv.z, 1.0f / dv.w};
    *(float4*)&invd[c0] = iv;
    float4 tv = {-sv.x * iv.x, -sv.y * iv.y, -sv.z * iv.z, -sv.w * iv.w};
    *(float4*)&tt[c0] = tv;
    __syncthreads();

    // seed: p_j = prod_{k=c_j}^{r0-2} t_k (first in-band iter supplies t_{r0-1})
    float p0 = 1.f, p1 = 1.f, p2 = 1.f, p3 = 1.f;
    for (int k = 0; k < r0 - 1; ++k) {
        float tm = tt[k];
        p0 = (k >= c0    ) ? p0 * tm : p0;
        p1 = (k >= c0 + 1) ? p1 * tm : p1;
        p2 = (k >= c0 + 2) ? p2 * tm : p2;
        p3 = (k >= c0 + 3) ? p3 * tm : p3;
    }
    p0 = (c0     < r0) ? p0 : 0.f;
    p1 = (c0 + 1 < r0) ? p1 : 0.f;
    p2 = (c0 + 2 < r0) ? p2 : 0.f;
    p3 = (c0 + 3 < r0) ? p3 : 0.f;

    float* orow = out + (size_t)bz * TT * TT + (size_t)r0 * TT + c0;

    #pragma unroll 2
    for (int r = r0; r < r0 + 64; ++r) {
        float tm = (r > 0) ? tt[r - 1] : 0.0f;
        p0 = (r == c0    ) ? 1.0f : p0 * tm;
        p1 = (r == c0 + 1) ? 1.0f : p1 * tm;
        p2 = (r == c0 + 2) ? 1.0f : p2 * tm;
        p3 = (r == c0 + 3) ? 1.0f : p3 * tm;
        float id = invd[r];
        vf4 v;
        v.x = p0 * id; v.y = p1 * id; v.z = p2 * id; v.w = p3 * id;
        v.x = isfinite(v.x) ? v.x : 0.0f;
        v.y = isfinite(v.y) ? v.y : 0.0f;
        v.z = isfinite(v.z) ? v.z : 0.0f;
        v.w = isfinite(v.w) ? v.w : 0.0f;
        __builtin_nontemporal_store(v, (vf4*)orow);
        orow += TT;
    }
}

extern "C" void kernel_launch(void* const* d_in, const int* in_sizes, int n_in,
                              void* d_out, int out_size, void* d_ws, size_t ws_size,
                              hipStream_t stream)
{
    const float* x  = (const float*)d_in[0];
    const float* W0 = (const float*)d_in[1];
    const float* b0 = (const float*)d_in[2];
    const float* W1 = (const float*)d_in[3];
    const float* b1 = (const float*)d_in[4];
    const float* W2 = (const float*)d_in[5];
    const float* b2 = (const float*)d_in[6];

    float* out = (float*)d_out;
    float* mu  = out;                         // (32,32,256)
    float* st  = out + BB * ZDIM * TT;        // (32,32,256,256)

    float* h0 = (float*)d_ws;                 // (32,256,256)
    float* h1 = h0 + BB * 256 * TT;           // (32,256,256)
    float* dd = h1 + BB * 256 * TT;           // (32,32,256)
    float* ss = dd + BB * ZDIM * TT;          // (32,32,256)

    // conv1: 64 -> 256, relu (fp32)
    conv_kernel<64, 256, 64, true, false><<<dim3(BB, 4, 4), 256, 0, stream>>>(
        x, W0, b0, h0, nullptr, nullptr, nullptr);
    // conv2: 256 -> 256, relu (bf16 MFMA, fp32 accumulate)
    conv2_mfma<<<dim3(BB, 4, 4), 256, 0, stream>>>(h0, W1, b1, h1);
    // conv3: 256 -> 96, stats (fp32)
    conv_kernel<256, 96, 32, false, true><<<dim3(BB, 3, 4), 256, 0, stream>>>(
        h1, W2, b2, nullptr, mu, dd, ss);
    // banded inverse-transpose, write-bound; 4 row-bands per (b,z)
    tril_kernel<<<dim3(BB * ZDIM, 4), 64, 0, stream>>>(dd, ss, st);
}

// Round 7
// 429.587 us; speedup vs baseline: 1.2294x; 1.0530x over previous
//
#include <hip/hip_runtime.h>
#include <hip/hip_bf16.h>
#include <math.h>

#define BB 32
#define TT 256
#define ZDIM 32

typedef float vf4 __attribute__((ext_vector_type(4)));
typedef float vf2 __attribute__((ext_vector_type(2)));
typedef short short8 __attribute__((ext_vector_type(8)));
typedef float f32x4 __attribute__((ext_vector_type(4)));

__device__ __forceinline__ float softplus_f(float v) {
    return fmaxf(v, 0.0f) + log1pf(expf(-fabsf(v)));
}

__device__ __forceinline__ short f2bf(float f) {
    __hip_bfloat16 h = __float2bfloat16(f);
    return *reinterpret_cast<short*>(&h);
}

// ---------------- fp32 conv (conv1 only; kept fp32 to bound accuracy drift) ----------------
template<int CIN, int COUT, int OTILE, bool RELU>
__global__ __launch_bounds__(256)
void conv_kernel(const float* __restrict__ x, const float* __restrict__ W,
                 const float* __restrict__ bias, float* __restrict__ y)
{
    constexpr int CT   = 32;
    constexpr int OPT  = OTILE / 16;
    constexpr int XST  = 68;
    static_assert(OPT == 4 || OPT == 2, "OPT must be 2 or 4");

    __shared__ float xs[CT][XST];
    __shared__ float ws[CT][3][OTILE];

    const int b  = blockIdx.x;
    const int o0 = blockIdx.y * OTILE;
    const int t0 = blockIdx.z * 64;

    const int tid = threadIdx.x;
    const int tg  = tid & 15;
    const int og  = tid >> 4;
    const int tb  = tg * 4;
    const int ob  = og * OPT;

    float acc[OPT][4];
    #pragma unroll
    for (int m = 0; m < OPT; ++m) {
        float bv = bias[o0 + ob + m];
        #pragma unroll
        for (int j = 0; j < 4; ++j) acc[m][j] = bv;
    }

    for (int c0 = 0; c0 < CIN; c0 += CT) {
        for (int idx = tid; idx < CT * 66; idx += 256) {
            int ci = idx / 66;
            int p  = idx - ci * 66;
            int t  = t0 - 1 + p;
            float v = 0.0f;
            if (t >= 0 && t < TT) v = x[(b * CIN + c0 + ci) * TT + t];
            xs[ci][p] = v;
        }
        for (int idx = tid; idx < OTILE * CT * 3; idx += 256) {
            int o  = idx / (CT * 3);
            int r2 = idx - o * (CT * 3);
            int ci = r2 / 3;
            int k  = r2 - ci * 3;
            ws[ci][k][o] = W[(o0 + o) * CIN * 3 + (c0 + ci) * 3 + k];
        }
        __syncthreads();

        #pragma unroll 4
        for (int ci = 0; ci < CT; ++ci) {
            vf4 xa = *(const vf4*)&xs[ci][tb];
            vf2 xb = *(const vf2*)&xs[ci][tb + 4];
            float xv[6] = {xa.x, xa.y, xa.z, xa.w, xb.x, xb.y};
            #pragma unroll
            for (int k = 0; k < 3; ++k) {
                float wv[OPT];
                if constexpr (OPT == 4) {
                    vf4 w = *(const vf4*)&ws[ci][k][ob];
                    wv[0] = w.x; wv[1] = w.y; wv[2] = w.z; wv[3] = w.w;
                } else {
                    vf2 w = *(const vf2*)&ws[ci][k][ob];
                    wv[0] = w.x; wv[1] = w.y;
                }
                #pragma unroll
                for (int m = 0; m < OPT; ++m)
                    #pragma unroll
                    for (int j = 0; j < 4; ++j)
                        acc[m][j] = fmaf(wv[m], xv[k + j], acc[m][j]);
            }
        }
        __syncthreads();
    }

    #pragma unroll
    for (int m = 0; m < OPT; ++m) {
        int o = o0 + ob + m;
        float4 v = {acc[m][0], acc[m][1], acc[m][2], acc[m][3]};
        if (RELU) {
            v.x = fmaxf(v.x, 0.f); v.y = fmaxf(v.y, 0.f);
            v.z = fmaxf(v.z, 0.f); v.w = fmaxf(v.w, 0.f);
        }
        *(float4*)&y[(b * COUT + o) * TT + t0 + tb] = v;
    }
}

// ---------------- bf16 MFMA conv (conv2: relu->y, conv3: stats->mu/dd/ss) ----------------
// Conv as 3 shifted GEMMs: out[o][t] += sum_ci W[o][ci][k] * x[ci][t+k-1].
// Block = NW waves, each wave a 16o x 64t strip via 16x16x32 bf16 MFMA.
// LDS: x-tile transposed to [t+halo][ci] (k-shift = free row offset), W as
// [k][o][ci]; bf16, ci-rows padded to 72 (36 dwords) to break bank-stride.
// Layouts (m89-verified): A[m=lane&15][ci=quad*8+j], B[ci=quad*8+j][n=lane&15],
// C row = quad*4+reg, col = lane&15.
template<int CIN, int COUT, int NW, bool IS_STATS>
__global__ __launch_bounds__(NW * 64)
void convm(const float* __restrict__ x, const float* __restrict__ W,
           const float* __restrict__ bias, float* __restrict__ y,
           float* __restrict__ out_mu, float* __restrict__ dd,
           float* __restrict__ ss)
{
    constexpr int NT  = NW * 64;   // threads per block
    constexpr int OB  = NW * 16;   // o per block
    constexpr int CT  = 64;        // ci chunk
    constexpr int PAD = 72;

    __shared__ short xsb[66][PAD];       // [p = t-halo][ci]
    __shared__ short wsb[3][OB][PAD];    // [k][o][ci]

    const int b    = blockIdx.x;
    const int o0   = blockIdx.y * OB;
    const int t0   = blockIdx.z * 64;
    const int tid  = threadIdx.x;
    const int wv   = tid >> 6;
    const int lane = tid & 63;
    const int l15  = lane & 15;
    const int quad = lane >> 4;

    f32x4 acc[4];
    {
        f32x4 bv;
        #pragma unroll
        for (int r = 0; r < 4; ++r) bv[r] = bias[o0 + wv * 16 + quad * 4 + r];
        #pragma unroll
        for (int nt = 0; nt < 4; ++nt) acc[nt] = bv;
    }

    for (int c0 = 0; c0 < CIN; c0 += CT) {
        if (c0) __syncthreads();
        // stage x tile: coalesced global read along t, bf16, transposed write
        for (int idx = tid; idx < CT * 66; idx += NT) {
            int ci = idx / 66;
            int p  = idx - ci * 66;
            int t  = t0 - 1 + p;
            float v = (t >= 0 && t < TT) ? x[(b * CIN + c0 + ci) * TT + t] : 0.f;
            xsb[p][ci] = f2bf(v);
        }
        // stage weights: 192 consecutive floats per o
        for (int idx = tid; idx < OB * 192; idx += NT) {
            int o = idx / 192;
            int r = idx - o * 192;
            int ci = r / 3;
            int k  = r - ci * 3;
            wsb[k][o][ci] = f2bf(W[(o0 + o) * (CIN * 3) + (c0 + ci) * 3 + k]);
        }
        __syncthreads();

        #pragma unroll
        for (int ks = 0; ks < 3; ++ks) {
            #pragma unroll
            for (int kc = 0; kc < CT; kc += 32) {
                short8 af = *(const short8*)&wsb[ks][wv * 16 + l15][kc + quad * 8];
                #pragma unroll
                for (int nt = 0; nt < 4; ++nt) {
                    short8 bf = *(const short8*)&xsb[nt * 16 + l15 + ks][kc + quad * 8];
                    acc[nt] = __builtin_amdgcn_mfma_f32_16x16x32_bf16(af, bf, acc[nt], 0, 0, 0);
                }
            }
        }
    }

    if constexpr (!IS_STATS) {
        // relu + store (16 lanes consecutive in t -> 64 B segments)
        #pragma unroll
        for (int nt = 0; nt < 4; ++nt) {
            int t = t0 + nt * 16 + l15;
            #pragma unroll
            for (int r = 0; r < 4; ++r) {
                int o = o0 + wv * 16 + quad * 4 + r;
                y[(b * COUT + o) * TT + t] = fmaxf(acc[nt][r], 0.f);
            }
        }
    } else {
        // stats routing: o<32 -> mu; else softplus -> dd (even, +1) / ss (odd)
        #pragma unroll
        for (int nt = 0; nt < 4; ++nt) {
            int t = t0 + nt * 16 + l15;
            #pragma unroll
            for (int r = 0; r < 4; ++r) {
                int o = o0 + wv * 16 + quad * 4 + r;
                float val = acc[nt][r];
                if (o < ZDIM) {
                    out_mu[(b * ZDIM + o) * TT + t] = val;
                } else {
                    int oc = o - ZDIM;
                    int z  = oc >> 1;
                    float sp = softplus_f(val);
                    if ((oc & 1) == 0) dd[(b * ZDIM + z) * TT + t] = sp + 1.f;
                    else               ss[(b * ZDIM + z) * TT + t] = sp;
                }
            }
        }
    }
}

// ---------------- banded inverse-transpose ----------------
__global__ __launch_bounds__(64)
void tril_kernel(const float* __restrict__ dd, const float* __restrict__ ss,
                 float* __restrict__ out)
{
    __shared__ float invd[TT];
    __shared__ float tt[TT];

    const int bz  = blockIdx.x;
    const int r0  = blockIdx.y * 64;
    const int tid = threadIdx.x;
    const int c0  = tid * 4;

    float4 dv = *(const float4*)&dd[bz * TT + c0];
    float4 sv = *(const float4*)&ss[bz * TT + c0];
    float4 iv = {1.0f / dv.x, 1.0f / dv.y, 1.0f / dv.z, 1.0f / dv.w};
    *(float4*)&invd[c0] = iv;
    float4 tv = {-sv.x * iv.x, -sv.y * iv.y, -sv.z * iv.z, -sv.w * iv.w};
    *(float4*)&tt[c0] = tv;
    __syncthreads();

    // seed: p_j = prod_{k=c_j}^{r0-2} t_k (first in-band iter supplies t_{r0-1})
    float p0 = 1.f, p1 = 1.f, p2 = 1.f, p3 = 1.f;
    for (int k = 0; k < r0 - 1; ++k) {
        float tm = tt[k];
        p0 = (k >= c0    ) ? p0 * tm : p0;
        p1 = (k >= c0 + 1) ? p1 * tm : p1;
        p2 = (k >= c0 + 2) ? p2 * tm : p2;
        p3 = (k >= c0 + 3) ? p3 * tm : p3;
    }
    p0 = (c0     < r0) ? p0 : 0.f;
    p1 = (c0 + 1 < r0) ? p1 : 0.f;
    p2 = (c0 + 2 < r0) ? p2 : 0.f;
    p3 = (c0 + 3 < r0) ? p3 : 0.f;

    float* orow = out + (size_t)bz * TT * TT + (size_t)r0 * TT + c0;

    #pragma unroll 2
    for (int r = r0; r < r0 + 64; ++r) {
        float tm = (r > 0) ? tt[r - 1] : 0.0f;
        p0 = (r == c0    ) ? 1.0f : p0 * tm;
        p1 = (r == c0 + 1) ? 1.0f : p1 * tm;
        p2 = (r == c0 + 2) ? 1.0f : p2 * tm;
        p3 = (r == c0 + 3) ? 1.0f : p3 * tm;
        float id = invd[r];
        vf4 v;
        v.x = p0 * id; v.y = p1 * id; v.z = p2 * id; v.w = p3 * id;
        v.x = isfinite(v.x) ? v.x : 0.0f;
        v.y = isfinite(v.y) ? v.y : 0.0f;
        v.z = isfinite(v.z) ? v.z : 0.0f;
        v.w = isfinite(v.w) ? v.w : 0.0f;
        __builtin_nontemporal_store(v, (vf4*)orow);
        orow += TT;
    }
}

extern "C" void kernel_launch(void* const* d_in, const int* in_sizes, int n_in,
                              void* d_out, int out_size, void* d_ws, size_t ws_size,
                              hipStream_t stream)
{
    const float* x  = (const float*)d_in[0];
    const float* W0 = (const float*)d_in[1];
    const float* b0 = (const float*)d_in[2];
    const float* W1 = (const float*)d_in[3];
    const float* b1 = (const float*)d_in[4];
    const float* W2 = (const float*)d_in[5];
    const float* b2 = (const float*)d_in[6];

    float* out = (float*)d_out;
    float* mu  = out;                         // (32,32,256)
    float* st  = out + BB * ZDIM * TT;        // (32,32,256,256)

    float* h0 = (float*)d_ws;                 // (32,256,256)
    float* h1 = h0 + BB * 256 * TT;           // (32,256,256)
    float* dd = h1 + BB * 256 * TT;           // (32,32,256)
    float* ss = dd + BB * ZDIM * TT;          // (32,32,256)

    // conv1: 64 -> 256, relu (fp32)
    conv_kernel<64, 256, 64, true><<<dim3(BB, 4, 4), 256, 0, stream>>>(
        x, W0, b0, h0);
    // conv2: 256 -> 256, relu (bf16 MFMA, fp32 accumulate)
    convm<256, 256, 4, false><<<dim3(BB, 4, 4), 256, 0, stream>>>(
        h0, W1, b1, h1, nullptr, nullptr, nullptr);
    // conv3: 256 -> 96, stats (bf16 MFMA): 2 blocks x 3 waves x 16o = 96o
    convm<256, 96, 3, true><<<dim3(BB, 2, 4), 192, 0, stream>>>(
        h1, W2, b2, nullptr, mu, dd, ss);
    // banded inverse-transpose, write-bound; 4 row-bands per (b,z)
    tril_kernel<<<dim3(BB * ZDIM, 4), 64, 0, stream>>>(dd, ss, st);
}

// Round 8
// 418.845 us; speedup vs baseline: 1.2609x; 1.0256x over previous
//
#include <hip/hip_runtime.h>
#include <hip/hip_bf16.h>
#include <math.h>

#define BB 32
#define TT 256
#define ZDIM 32

typedef float vf4 __attribute__((ext_vector_type(4)));
typedef short short8 __attribute__((ext_vector_type(8)));
typedef float f32x4 __attribute__((ext_vector_type(4)));

__device__ __forceinline__ float softplus_f(float v) {
    return fmaxf(v, 0.0f) + log1pf(expf(-fabsf(v)));
}

__device__ __forceinline__ short f2bf(float f) {
    __hip_bfloat16 h = __float2bfloat16(f);
    return *reinterpret_cast<short*>(&h);
}

// ---------------- bf16 MFMA conv (all three layers) ----------------
// Conv as 3 shifted GEMMs: out[o][t] += sum_ci W[o][ci][k] * x[ci][t+k-1].
// Block = NW waves, each wave a 16o x 64t strip via 16x16x32 bf16 MFMA.
// LDS: x-tile transposed to [t+halo][ci] (k-shift = free row offset), W as
// [k][o][ci]; bf16, ci-rows padded to 72 (36 dwords) to break bank-stride.
// Layouts (m89-verified): A[m=lane&15][ci=quad*8+j], B[ci=quad*8+j][n=lane&15],
// C row = quad*4+reg, col = lane&15.
// EPI: 0 = relu->y, 1 = stats (mu/softplus->dd,ss), used by conv3.
template<int CIN, int COUT, int NW, bool IS_STATS>
__global__ __launch_bounds__(NW * 64)
void convm(const float* __restrict__ x, const float* __restrict__ W,
           const float* __restrict__ bias, float* __restrict__ y,
           float* __restrict__ out_mu, float* __restrict__ dd,
           float* __restrict__ ss)
{
    constexpr int NT  = NW * 64;   // threads per block
    constexpr int OB  = NW * 16;   // o per block
    constexpr int CT  = 64;        // ci chunk (CIN=64 -> single chunk)
    constexpr int PAD = 72;

    __shared__ short xsb[66][PAD];       // [p = t-halo][ci]
    __shared__ short wsb[3][OB][PAD];    // [k][o][ci]

    const int b    = blockIdx.x;
    const int o0   = blockIdx.y * OB;
    const int t0   = blockIdx.z * 64;
    const int tid  = threadIdx.x;
    const int wv   = tid >> 6;
    const int lane = tid & 63;
    const int l15  = lane & 15;
    const int quad = lane >> 4;

    f32x4 acc[4];
    {
        f32x4 bv;
        #pragma unroll
        for (int r = 0; r < 4; ++r) bv[r] = bias[o0 + wv * 16 + quad * 4 + r];
        #pragma unroll
        for (int nt = 0; nt < 4; ++nt) acc[nt] = bv;
    }

    for (int c0 = 0; c0 < CIN; c0 += CT) {
        if (c0) __syncthreads();
        // stage x tile: coalesced global read along t, bf16, transposed write
        for (int idx = tid; idx < CT * 66; idx += NT) {
            int ci = idx / 66;
            int p  = idx - ci * 66;
            int t  = t0 - 1 + p;
            float v = (t >= 0 && t < TT) ? x[(b * CIN + c0 + ci) * TT + t] : 0.f;
            xsb[p][ci] = f2bf(v);
        }
        // stage weights: CT*3 = 192 consecutive floats per o within this chunk
        for (int idx = tid; idx < OB * (CT * 3); idx += NT) {
            int o = idx / (CT * 3);
            int r = idx - o * (CT * 3);
            int ci = r / 3;
            int k  = r - ci * 3;
            wsb[k][o][ci] = f2bf(W[(o0 + o) * (CIN * 3) + (c0 + ci) * 3 + k]);
        }
        __syncthreads();

        #pragma unroll
        for (int ks = 0; ks < 3; ++ks) {
            #pragma unroll
            for (int kc = 0; kc < CT; kc += 32) {
                short8 af = *(const short8*)&wsb[ks][wv * 16 + l15][kc + quad * 8];
                #pragma unroll
                for (int nt = 0; nt < 4; ++nt) {
                    short8 bf = *(const short8*)&xsb[nt * 16 + l15 + ks][kc + quad * 8];
                    acc[nt] = __builtin_amdgcn_mfma_f32_16x16x32_bf16(af, bf, acc[nt], 0, 0, 0);
                }
            }
        }
    }

    if constexpr (!IS_STATS) {
        // relu + store (16 lanes consecutive in t -> 64 B segments)
        #pragma unroll
        for (int nt = 0; nt < 4; ++nt) {
            int t = t0 + nt * 16 + l15;
            #pragma unroll
            for (int r = 0; r < 4; ++r) {
                int o = o0 + wv * 16 + quad * 4 + r;
                y[(b * COUT + o) * TT + t] = fmaxf(acc[nt][r], 0.f);
            }
        }
    } else {
        // stats routing: o<32 -> mu; else softplus -> dd (even, +1) / ss (odd)
        #pragma unroll
        for (int nt = 0; nt < 4; ++nt) {
            int t = t0 + nt * 16 + l15;
            #pragma unroll
            for (int r = 0; r < 4; ++r) {
                int o = o0 + wv * 16 + quad * 4 + r;
                float val = acc[nt][r];
                if (o < ZDIM) {
                    out_mu[(b * ZDIM + o) * TT + t] = val;
                } else {
                    int oc = o - ZDIM;
                    int z  = oc >> 1;
                    float sp = softplus_f(val);
                    if ((oc & 1) == 0) dd[(b * ZDIM + z) * TT + t] = sp + 1.f;
                    else               ss[(b * ZDIM + z) * TT + t] = sp;
                }
            }
        }
    }
}

// ---------------- banded inverse-transpose ----------------
// scale_tril[r,c] = invd[r] * prod_{k=c}^{r-1} t_k (t_k = -s_k/d_k), 0 above diag.
// Grid (bz, band): wave handles 64 rows; seed = prod_{k=c}^{r0-2} t_k (first
// in-band iter supplies t_{r0-1}); ascending order -> bit-identical to 1-wave.
__global__ __launch_bounds__(64)
void tril_kernel(const float* __restrict__ dd, const float* __restrict__ ss,
                 float* __restrict__ out)
{
    __shared__ float invd[TT];
    __shared__ float tt[TT];

    const int bz  = blockIdx.x;
    const int r0  = blockIdx.y * 64;
    const int tid = threadIdx.x;
    const int c0  = tid * 4;

    float4 dv = *(const float4*)&dd[bz * TT + c0];
    float4 sv = *(const float4*)&ss[bz * TT + c0];
    float4 iv = {1.0f / dv.x, 1.0f / dv.y, 1.0f / dv.z, 1.0f / dv.w};
    *(float4*)&invd[c0] = iv;
    float4 tv = {-sv.x * iv.x, -sv.y * iv.y, -sv.z * iv.z, -sv.w * iv.w};
    *(float4*)&tt[c0] = tv;
    __syncthreads();

    float p0 = 1.f, p1 = 1.f, p2 = 1.f, p3 = 1.f;
    for (int k = 0; k < r0 - 1; ++k) {
        float tm = tt[k];
        p0 = (k >= c0    ) ? p0 * tm : p0;
        p1 = (k >= c0 + 1) ? p1 * tm : p1;
        p2 = (k >= c0 + 2) ? p2 * tm : p2;
        p3 = (k >= c0 + 3) ? p3 * tm : p3;
    }
    p0 = (c0     < r0) ? p0 : 0.f;
    p1 = (c0 + 1 < r0) ? p1 : 0.f;
    p2 = (c0 + 2 < r0) ? p2 : 0.f;
    p3 = (c0 + 3 < r0) ? p3 : 0.f;

    float* orow = out + (size_t)bz * TT * TT + (size_t)r0 * TT + c0;

    #pragma unroll 2
    for (int r = r0; r < r0 + 64; ++r) {
        float tm = (r > 0) ? tt[r - 1] : 0.0f;
        p0 = (r == c0    ) ? 1.0f : p0 * tm;
        p1 = (r == c0 + 1) ? 1.0f : p1 * tm;
        p2 = (r == c0 + 2) ? 1.0f : p2 * tm;
        p3 = (r == c0 + 3) ? 1.0f : p3 * tm;
        float id = invd[r];
        vf4 v;
        v.x = p0 * id; v.y = p1 * id; v.z = p2 * id; v.w = p3 * id;
        v.x = isfinite(v.x) ? v.x : 0.0f;
        v.y = isfinite(v.y) ? v.y : 0.0f;
        v.z = isfinite(v.z) ? v.z : 0.0f;
        v.w = isfinite(v.w) ? v.w : 0.0f;
        __builtin_nontemporal_store(v, (vf4*)orow);
        orow += TT;
    }
}

extern "C" void kernel_launch(void* const* d_in, const int* in_sizes, int n_in,
                              void* d_out, int out_size, void* d_ws, size_t ws_size,
                              hipStream_t stream)
{
    const float* x  = (const float*)d_in[0];
    const float* W0 = (const float*)d_in[1];
    const float* b0 = (const float*)d_in[2];
    const float* W1 = (const float*)d_in[3];
    const float* b1 = (const float*)d_in[4];
    const float* W2 = (const float*)d_in[5];
    const float* b2 = (const float*)d_in[6];

    float* out = (float*)d_out;
    float* mu  = out;                         // (32,32,256)
    float* st  = out + BB * ZDIM * TT;        // (32,32,256,256)

    float* h0 = (float*)d_ws;                 // (32,256,256)
    float* h1 = h0 + BB * 256 * TT;           // (32,256,256)
    float* dd = h1 + BB * 256 * TT;           // (32,32,256)
    float* ss = dd + BB * ZDIM * TT;          // (32,32,256)

    // conv1: 64 -> 256, relu (bf16 MFMA; CIN=64 = single K-chunk)
    convm<64, 256, 4, false><<<dim3(BB, 4, 4), 256, 0, stream>>>(
        x, W0, b0, h0, nullptr, nullptr, nullptr);
    // conv2: 256 -> 256, relu (bf16 MFMA)
    convm<256, 256, 4, false><<<dim3(BB, 4, 4), 256, 0, stream>>>(
        h0, W1, b1, h1, nullptr, nullptr, nullptr);
    // conv3: 256 -> 96, stats (bf16 MFMA): 2 blocks x 3 waves x 16o = 96o
    convm<256, 96, 3, true><<<dim3(BB, 2, 4), 192, 0, stream>>>(
        h1, W2, b2, nullptr, mu, dd, ss);
    // banded inverse-transpose, write-bound; 4 row-bands per (b,z)
    tril_kernel<<<dim3(BB * ZDIM, 4), 64, 0, stream>>>(dd, ss, st);
}

// Round 9
// 385.504 us; speedup vs baseline: 1.3699x; 1.0865x over previous
//
#include <hip/hip_runtime.h>
#include <hip/hip_bf16.h>
#include <math.h>

#define BB 32
#define TT 256
#define ZDIM 32

typedef float vf4 __attribute__((ext_vector_type(4)));
typedef short short8 __attribute__((ext_vector_type(8)));
typedef short short4v __attribute__((ext_vector_type(4)));
typedef float f32x4 __attribute__((ext_vector_type(4)));

__device__ __forceinline__ float softplus_f(float v) {
    return fmaxf(v, 0.0f) + log1pf(expf(-fabsf(v)));
}

__device__ __forceinline__ unsigned short f2bf(float f) {
    __hip_bfloat16 h = __float2bfloat16(f);
    return *reinterpret_cast<unsigned short*>(&h);
}

// ---------------- weight preconvert: W[o][ci][k] fp32 -> Wb[k][o][ci] bf16 ----------------
template<int COUT, int CIN>
__device__ void wconv_one(const float* __restrict__ W, unsigned short* __restrict__ Wb,
                          int tid, int nthreads)
{
    const int n = 3 * COUT * CIN;
    for (int idx = tid; idx < n; idx += nthreads) {
        int ci = idx % CIN;
        int q  = idx / CIN;
        int o  = q % COUT;
        int k  = q / COUT;
        Wb[idx] = f2bf(W[o * (CIN * 3) + ci * 3 + k]);
    }
}

__global__ __launch_bounds__(256)
void wconv_kernel(const float* __restrict__ W0, const float* __restrict__ W1,
                  const float* __restrict__ W2, unsigned short* __restrict__ w0b,
                  unsigned short* __restrict__ w1b, unsigned short* __restrict__ w2b)
{
    const int tid = blockIdx.x * blockDim.x + threadIdx.x;
    const int nth = gridDim.x * blockDim.x;
    wconv_one<256, 64>(W0, w0b, tid, nth);
    wconv_one<256, 256>(W1, w1b, tid, nth);
    wconv_one<96, 256>(W2, w2b, tid, nth);
}

// ---------------- bf16 MFMA conv ----------------
// out[o][t] += sum_ci W[o][ci][k] * x[ci][t+k-1] as 3 shifted GEMMs.
// Block = NW waves, wave = 16o x 64t strip, 16x16x32 bf16 MFMA.
// LDS: x transposed [t+halo][ci] (k-shift = free row offset), W staged from
// preconverted Wb[k][o][ci] via short4 vector copies (no converts). ci-rows
// padded to 72 shorts (36 dwords): 2-way bank aliasing only (free, m136).
// Layouts (m89): A[m=lane&15][ci=quad*8+j], B[ci=quad*8+j][n=lane&15],
// C row = quad*4+reg, col = lane&15.
// XBF16: input is bf16 (h0b/h1b) vs fp32 (original x). !IS_STATS: bf16 relu out.
template<int CIN, int COUT, int NW, bool IS_STATS, bool XBF16>
__global__ __launch_bounds__(NW * 64)
void convm(const void* __restrict__ xin, const unsigned short* __restrict__ Wb,
           const float* __restrict__ bias, unsigned short* __restrict__ y,
           float* __restrict__ out_mu, float* __restrict__ dd,
           float* __restrict__ ss)
{
    constexpr int NT  = NW * 64;
    constexpr int OB  = NW * 16;
    constexpr int CT  = 64;
    constexpr int PAD = 72;

    __shared__ unsigned short xsb[66][PAD];     // [p = t-halo][ci]
    __shared__ unsigned short wsb[3][OB][PAD];  // [k][o][ci]

    const int b    = blockIdx.x;
    const int o0   = blockIdx.y * OB;
    const int t0   = blockIdx.z * 64;
    const int tid  = threadIdx.x;
    const int wv   = tid >> 6;
    const int lane = tid & 63;
    const int l15  = lane & 15;
    const int quad = lane >> 4;

    f32x4 acc[4];
    {
        f32x4 bv;
        #pragma unroll
        for (int r = 0; r < 4; ++r) bv[r] = bias[o0 + wv * 16 + quad * 4 + r];
        #pragma unroll
        for (int nt = 0; nt < 4; ++nt) acc[nt] = bv;
    }

    for (int c0 = 0; c0 < CIN; c0 += CT) {
        if (c0) __syncthreads();
        // stage x tile (transposed write). bf16 zero == 0x0000.
        for (int idx = tid; idx < CT * 66; idx += NT) {
            int ci = idx / 66;
            int p  = idx - ci * 66;
            int t  = t0 - 1 + p;
            unsigned short v = 0;
            if (t >= 0 && t < TT) {
                if constexpr (XBF16)
                    v = ((const unsigned short*)xin)[(b * CIN + c0 + ci) * TT + t];
                else
                    v = f2bf(((const float*)xin)[(b * CIN + c0 + ci) * TT + t]);
            }
            xsb[p][ci] = v;
        }
        // stage weights: short4 (8 B) vector copies from Wb[k][o][ci].
        // row start (k*COUT+o)*CIN + c0 is 64-short aligned; LDS dest offset
        // cv*4 shorts from a 144 B row base -> 8 B aligned. 12 copies/thread.
        for (int idx = tid; idx < 3 * OB * (CT / 4); idx += NT) {
            int cv = idx % (CT / 4);
            int q  = idx / (CT / 4);
            int o  = q % OB;
            int k  = q / OB;
            short4v v = *(const short4v*)&Wb[((k * COUT) + o0 + o) * CIN + c0 + cv * 4];
            *(short4v*)&wsb[k][o][cv * 4] = v;
        }
        __syncthreads();

        #pragma unroll
        for (int ks = 0; ks < 3; ++ks) {
            #pragma unroll
            for (int kc = 0; kc < CT; kc += 32) {
                short8 af = *(const short8*)&wsb[ks][wv * 16 + l15][kc + quad * 8];
                #pragma unroll
                for (int nt = 0; nt < 4; ++nt) {
                    short8 bf = *(const short8*)&xsb[nt * 16 + l15 + ks][kc + quad * 8];
                    acc[nt] = __builtin_amdgcn_mfma_f32_16x16x32_bf16(af, bf, acc[nt], 0, 0, 0);
                }
            }
        }
    }

    if constexpr (!IS_STATS) {
        // relu -> bf16 store (identical rounding to old staging-time convert)
        #pragma unroll
        for (int nt = 0; nt < 4; ++nt) {
            int t = t0 + nt * 16 + l15;
            #pragma unroll
            for (int r = 0; r < 4; ++r) {
                int o = o0 + wv * 16 + quad * 4 + r;
                y[(b * COUT + o) * TT + t] = f2bf(fmaxf(acc[nt][r], 0.f));
            }
        }
    } else {
        // stats: o<32 -> mu (fp32); else softplus -> dd (even, +1) / ss (odd)
        #pragma unroll
        for (int nt = 0; nt < 4; ++nt) {
            int t = t0 + nt * 16 + l15;
            #pragma unroll
            for (int r = 0; r < 4; ++r) {
                int o = o0 + wv * 16 + quad * 4 + r;
                float val = acc[nt][r];
                if (o < ZDIM) {
                    out_mu[(b * ZDIM + o) * TT + t] = val;
                } else {
                    int oc = o - ZDIM;
                    int z  = oc >> 1;
                    float sp = softplus_f(val);
                    if ((oc & 1) == 0) dd[(b * ZDIM + z) * TT + t] = sp + 1.f;
                    else               ss[(b * ZDIM + z) * TT + t] = sp;
                }
            }
        }
    }
}

// ---------------- banded inverse-transpose ----------------
// scale_tril[r,c] = invd[r] * prod_{k=c}^{r-1} t_k (t_k = -s_k/d_k), 0 above diag.
// Grid (bz, band): wave handles 64 rows; seed = prod_{k=c}^{r0-2} t_k (first
// in-band iter supplies t_{r0-1}); ascending order -> bit-identical to 1-wave.
__global__ __launch_bounds__(64)
void tril_kernel(const float* __restrict__ dd, const float* __restrict__ ss,
                 float* __restrict__ out)
{
    __shared__ float invd[TT];
    __shared__ float tt[TT];

    const int bz  = blockIdx.x;
    const int r0  = blockIdx.y * 64;
    const int tid = threadIdx.x;
    const int c0  = tid * 4;

    float4 dv = *(const float4*)&dd[bz * TT + c0];
    float4 sv = *(const float4*)&ss[bz * TT + c0];
    float4 iv = {1.0f / dv.x, 1.0f / dv.y, 1.0f / dv.z, 1.0f / dv.w};
    *(float4*)&invd[c0] = iv;
    float4 tv = {-sv.x * iv.x, -sv.y * iv.y, -sv.z * iv.z, -sv.w * iv.w};
    *(float4*)&tt[c0] = tv;
    __syncthreads();

    float p0 = 1.f, p1 = 1.f, p2 = 1.f, p3 = 1.f;
    for (int k = 0; k < r0 - 1; ++k) {
        float tm = tt[k];
        p0 = (k >= c0    ) ? p0 * tm : p0;
        p1 = (k >= c0 + 1) ? p1 * tm : p1;
        p2 = (k >= c0 + 2) ? p2 * tm : p2;
        p3 = (k >= c0 + 3) ? p3 * tm : p3;
    }
    p0 = (c0     < r0) ? p0 : 0.f;
    p1 = (c0 + 1 < r0) ? p1 : 0.f;
    p2 = (c0 + 2 < r0) ? p2 : 0.f;
    p3 = (c0 + 3 < r0) ? p3 : 0.f;

    float* orow = out + (size_t)bz * TT * TT + (size_t)r0 * TT + c0;

    #pragma unroll 2
    for (int r = r0; r < r0 + 64; ++r) {
        float tm = (r > 0) ? tt[r - 1] : 0.0f;
        p0 = (r == c0    ) ? 1.0f : p0 * tm;
        p1 = (r == c0 + 1) ? 1.0f : p1 * tm;
        p2 = (r == c0 + 2) ? 1.0f : p2 * tm;
        p3 = (r == c0 + 3) ? 1.0f : p3 * tm;
        float id = invd[r];
        vf4 v;
        v.x = p0 * id; v.y = p1 * id; v.z = p2 * id; v.w = p3 * id;
        v.x = isfinite(v.x) ? v.x : 0.0f;
        v.y = isfinite(v.y) ? v.y : 0.0f;
        v.z = isfinite(v.z) ? v.z : 0.0f;
        v.w = isfinite(v.w) ? v.w : 0.0f;
        __builtin_nontemporal_store(v, (vf4*)orow);
        orow += TT;
    }
}

extern "C" void kernel_launch(void* const* d_in, const int* in_sizes, int n_in,
                              void* d_out, int out_size, void* d_ws, size_t ws_size,
                              hipStream_t stream)
{
    const float* x  = (const float*)d_in[0];
    const float* W0 = (const float*)d_in[1];
    const float* b0 = (const float*)d_in[2];
    const float* W1 = (const float*)d_in[3];
    const float* b1 = (const float*)d_in[4];
    const float* W2 = (const float*)d_in[5];
    const float* b2 = (const float*)d_in[6];

    float* out = (float*)d_out;
    float* mu  = out;                          // (32,32,256)
    float* st  = out + BB * ZDIM * TT;         // (32,32,256,256)

    // workspace layout (bf16 intermediates + fp32 dd/ss + bf16 weights)
    unsigned short* h0b = (unsigned short*)d_ws;          // 2,097,152 shorts (4 MB)
    unsigned short* h1b = h0b + BB * 256 * TT;            // 2,097,152 shorts
    float* dd  = (float*)(h1b + BB * 256 * TT);           // 262,144 floats
    float* ss  = dd + BB * ZDIM * TT;                     // 262,144 floats
    unsigned short* w0b = (unsigned short*)(ss + BB * ZDIM * TT);  // 3*256*64
    unsigned short* w1b = w0b + 3 * 256 * 64;                      // 3*256*256
    unsigned short* w2b = w1b + 3 * 256 * 256;                     // 3*96*256

    // weight preconvert + transpose to [k][o][ci] bf16
    wconv_kernel<<<dim3(256), 256, 0, stream>>>(W0, W1, W2, w0b, w1b, w2b);
    // conv1: 64 -> 256, relu (fp32 in, bf16 out)
    convm<64, 256, 4, false, false><<<dim3(BB, 4, 4), 256, 0, stream>>>(
        x, w0b, b0, h0b, nullptr, nullptr, nullptr);
    // conv2: 256 -> 256, relu (bf16 in/out)
    convm<256, 256, 4, false, true><<<dim3(BB, 4, 4), 256, 0, stream>>>(
        h0b, w1b, b1, h1b, nullptr, nullptr, nullptr);
    // conv3: 256 -> 96, stats (bf16 in, fp32 mu/dd/ss out)
    convm<256, 96, 3, true, true><<<dim3(BB, 2, 4), 192, 0, stream>>>(
        h1b, w2b, b2, nullptr, mu, dd, ss);
    // banded inverse-transpose, write-bound; 4 row-bands per (b,z)
    tril_kernel<<<dim3(BB * ZDIM, 4), 64, 0, stream>>>(dd, ss, st);
}

// Round 10
// 375.787 us; speedup vs baseline: 1.4054x; 1.0259x over previous
//
#include <hip/hip_runtime.h>
#include <hip/hip_bf16.h>
#include <math.h>

#define BB 32
#define TT 256
#define ZDIM 32

typedef float vf4 __attribute__((ext_vector_type(4)));
typedef short short8 __attribute__((ext_vector_type(8)));
typedef short short4v __attribute__((ext_vector_type(4)));
typedef float f32x4 __attribute__((ext_vector_type(4)));

__device__ __forceinline__ float softplus_f(float v) {
    return fmaxf(v, 0.0f) + log1pf(expf(-fabsf(v)));
}

__device__ __forceinline__ unsigned short f2bf(float f) {
    __hip_bfloat16 h = __float2bfloat16(f);
    return *reinterpret_cast<unsigned short*>(&h);
}

// ---------------- weight preconvert: W[o][ci][k] fp32 -> Wb[k][o][ci] bf16 ----------------
template<int COUT, int CIN>
__device__ void wconv_one(const float* __restrict__ W, unsigned short* __restrict__ Wb,
                          int tid, int nthreads)
{
    const int n = 3 * COUT * CIN;
    for (int idx = tid; idx < n; idx += nthreads) {
        int ci = idx % CIN;
        int q  = idx / CIN;
        int o  = q % COUT;
        int k  = q / COUT;
        Wb[idx] = f2bf(W[o * (CIN * 3) + ci * 3 + k]);
    }
}

__global__ __launch_bounds__(256)
void wconv_kernel(const float* __restrict__ W0, const float* __restrict__ W1,
                  const float* __restrict__ W2, unsigned short* __restrict__ w0b,
                  unsigned short* __restrict__ w1b, unsigned short* __restrict__ w2b)
{
    const int tid = blockIdx.x * blockDim.x + threadIdx.x;
    const int nth = gridDim.x * blockDim.x;
    wconv_one<256, 64>(W0, w0b, tid, nth);
    wconv_one<256, 256>(W1, w1b, tid, nth);
    wconv_one<96, 256>(W2, w2b, tid, nth);
}

// ---------------- bf16 MFMA conv ----------------
// out[o][t] += sum_ci W[o][ci][k] * x[ci][t+k-1] as 3 shifted GEMMs.
// Block = NW waves, wave = 16o x 64t strip, 16x16x32 bf16 MFMA.
// NW=8 (conv1/conv2): 128 outputs/block -> x and W staging per output halved
// vs NW=4, at identical 8 waves/CU occupancy (61.7 KB LDS, grid 256 = 1/CU).
// LDS: x transposed [t+halo][ci] PAD 72 (b128-aligned fragment reads), W
// [k][o][ci] PAD 68 (fits 64 KB; af reads split to 2x ds_read_b64 - minor).
// Layouts (m89): A[m=lane&15][ci=quad*8+j], B[ci=quad*8+j][n=lane&15],
// C row = quad*4+reg, col = lane&15.
template<int CIN, int COUT, int NW, bool IS_STATS, bool XBF16>
__global__ __launch_bounds__(NW * 64)
void convm(const void* __restrict__ xin, const unsigned short* __restrict__ Wb,
           const float* __restrict__ bias, unsigned short* __restrict__ y,
           float* __restrict__ out_mu, float* __restrict__ dd,
           float* __restrict__ ss)
{
    constexpr int NT   = NW * 64;
    constexpr int OB   = NW * 16;
    constexpr int CT   = 64;
    constexpr int XPAD = 72;   // 144 B rows: 16B-aligned b128 reads
    constexpr int WPAD = 68;   // 136 B rows: fits 64 KB at OB=128

    __shared__ unsigned short xsb[66][XPAD];     // [p = t-halo][ci]
    __shared__ unsigned short wsb[3][OB][WPAD];  // [k][o][ci]

    const int b    = blockIdx.x;
    const int o0   = blockIdx.y * OB;
    const int t0   = blockIdx.z * 64;
    const int tid  = threadIdx.x;
    const int wv   = tid >> 6;
    const int lane = tid & 63;
    const int l15  = lane & 15;
    const int quad = lane >> 4;

    f32x4 acc[4];
    {
        f32x4 bv;
        #pragma unroll
        for (int r = 0; r < 4; ++r) bv[r] = bias[o0 + wv * 16 + quad * 4 + r];
        #pragma unroll
        for (int nt = 0; nt < 4; ++nt) acc[nt] = bv;
    }

    for (int c0 = 0; c0 < CIN; c0 += CT) {
        if (c0) __syncthreads();
        // stage x tile (transposed write). bf16 zero == 0x0000.
        for (int idx = tid; idx < CT * 66; idx += NT) {
            int ci = idx / 66;
            int p  = idx - ci * 66;
            int t  = t0 - 1 + p;
            unsigned short v = 0;
            if (t >= 0 && t < TT) {
                if constexpr (XBF16)
                    v = ((const unsigned short*)xin)[(b * CIN + c0 + ci) * TT + t];
                else
                    v = f2bf(((const float*)xin)[(b * CIN + c0 + ci) * TT + t]);
            }
            xsb[p][ci] = v;
        }
        // stage weights: short4 (8 B) vector copies from Wb[k][o][ci]
        for (int idx = tid; idx < 3 * OB * (CT / 4); idx += NT) {
            int cv = idx % (CT / 4);
            int q  = idx / (CT / 4);
            int o  = q % OB;
            int k  = q / OB;
            short4v v = *(const short4v*)&Wb[((k * COUT) + o0 + o) * CIN + c0 + cv * 4];
            *(short4v*)&wsb[k][o][cv * 4] = v;
        }
        __syncthreads();

        #pragma unroll
        for (int ks = 0; ks < 3; ++ks) {
            #pragma unroll
            for (int kc = 0; kc < CT; kc += 32) {
                short8 af = *(const short8*)&wsb[ks][wv * 16 + l15][kc + quad * 8];
                #pragma unroll
                for (int nt = 0; nt < 4; ++nt) {
                    short8 bf = *(const short8*)&xsb[nt * 16 + l15 + ks][kc + quad * 8];
                    acc[nt] = __builtin_amdgcn_mfma_f32_16x16x32_bf16(af, bf, acc[nt], 0, 0, 0);
                }
            }
        }
    }

    if constexpr (!IS_STATS) {
        // relu -> bf16 store (identical rounding to staging-time convert)
        #pragma unroll
        for (int nt = 0; nt < 4; ++nt) {
            int t = t0 + nt * 16 + l15;
            #pragma unroll
            for (int r = 0; r < 4; ++r) {
                int o = o0 + wv * 16 + quad * 4 + r;
                y[(b * COUT + o) * TT + t] = f2bf(fmaxf(acc[nt][r], 0.f));
            }
        }
    } else {
        // stats: o<32 -> mu (fp32); else softplus -> dd (even, +1) / ss (odd)
        #pragma unroll
        for (int nt = 0; nt < 4; ++nt) {
            int t = t0 + nt * 16 + l15;
            #pragma unroll
            for (int r = 0; r < 4; ++r) {
                int o = o0 + wv * 16 + quad * 4 + r;
                float val = acc[nt][r];
                if (o < ZDIM) {
                    out_mu[(b * ZDIM + o) * TT + t] = val;
                } else {
                    int oc = o - ZDIM;
                    int z  = oc >> 1;
                    float sp = softplus_f(val);
                    if ((oc & 1) == 0) dd[(b * ZDIM + z) * TT + t] = sp + 1.f;
                    else               ss[(b * ZDIM + z) * TT + t] = sp;
                }
            }
        }
    }
}

// ---------------- banded inverse-transpose ----------------
// scale_tril[r,c] = invd[r] * prod_{k=c}^{r-1} t_k (t_k = -s_k/d_k), 0 above diag.
// Grid (bz, band): wave handles 64 rows; seed = prod_{k=c}^{r0-2} t_k (first
// in-band iter supplies t_{r0-1}); ascending order -> bit-identical to 1-wave.
__global__ __launch_bounds__(64)
void tril_kernel(const float* __restrict__ dd, const float* __restrict__ ss,
                 float* __restrict__ out)
{
    __shared__ float invd[TT];
    __shared__ float tt[TT];

    const int bz  = blockIdx.x;
    const int r0  = blockIdx.y * 64;
    const int tid = threadIdx.x;
    const int c0  = tid * 4;

    float4 dv = *(const float4*)&dd[bz * TT + c0];
    float4 sv = *(const float4*)&ss[bz * TT + c0];
    float4 iv = {1.0f / dv.x, 1.0f / dv.y, 1.0f / dv.z, 1.0f / dv.w};
    *(float4*)&invd[c0] = iv;
    float4 tv = {-sv.x * iv.x, -sv.y * iv.y, -sv.z * iv.z, -sv.w * iv.w};
    *(float4*)&tt[c0] = tv;
    __syncthreads();

    float p0 = 1.f, p1 = 1.f, p2 = 1.f, p3 = 1.f;
    for (int k = 0; k < r0 - 1; ++k) {
        float tm = tt[k];
        p0 = (k >= c0    ) ? p0 * tm : p0;
        p1 = (k >= c0 + 1) ? p1 * tm : p1;
        p2 = (k >= c0 + 2) ? p2 * tm : p2;
        p3 = (k >= c0 + 3) ? p3 * tm : p3;
    }
    p0 = (c0     < r0) ? p0 : 0.f;
    p1 = (c0 + 1 < r0) ? p1 : 0.f;
    p2 = (c0 + 2 < r0) ? p2 : 0.f;
    p3 = (c0 + 3 < r0) ? p3 : 0.f;

    float* orow = out + (size_t)bz * TT * TT + (size_t)r0 * TT + c0;

    #pragma unroll 2
    for (int r = r0; r < r0 + 64; ++r) {
        float tm = (r > 0) ? tt[r - 1] : 0.0f;
        p0 = (r == c0    ) ? 1.0f : p0 * tm;
        p1 = (r == c0 + 1) ? 1.0f : p1 * tm;
        p2 = (r == c0 + 2) ? 1.0f : p2 * tm;
        p3 = (r == c0 + 3) ? 1.0f : p3 * tm;
        float id = invd[r];
        vf4 v;
        v.x = p0 * id; v.y = p1 * id; v.z = p2 * id; v.w = p3 * id;
        v.x = isfinite(v.x) ? v.x : 0.0f;
        v.y = isfinite(v.y) ? v.y : 0.0f;
        v.z = isfinite(v.z) ? v.z : 0.0f;
        v.w = isfinite(v.w) ? v.w : 0.0f;
        __builtin_nontemporal_store(v, (vf4*)orow);
        orow += TT;
    }
}

extern "C" void kernel_launch(void* const* d_in, const int* in_sizes, int n_in,
                              void* d_out, int out_size, void* d_ws, size_t ws_size,
                              hipStream_t stream)
{
    const float* x  = (const float*)d_in[0];
    const float* W0 = (const float*)d_in[1];
    const float* b0 = (const float*)d_in[2];
    const float* W1 = (const float*)d_in[3];
    const float* b1 = (const float*)d_in[4];
    const float* W2 = (const float*)d_in[5];
    const float* b2 = (const float*)d_in[6];

    float* out = (float*)d_out;
    float* mu  = out;                          // (32,32,256)
    float* st  = out + BB * ZDIM * TT;         // (32,32,256,256)

    // workspace layout (bf16 intermediates + fp32 dd/ss + bf16 weights)
    unsigned short* h0b = (unsigned short*)d_ws;          // 2,097,152 shorts (4 MB)
    unsigned short* h1b = h0b + BB * 256 * TT;            // 2,097,152 shorts
    float* dd  = (float*)(h1b + BB * 256 * TT);           // 262,144 floats
    float* ss  = dd + BB * ZDIM * TT;                     // 262,144 floats
    unsigned short* w0b = (unsigned short*)(ss + BB * ZDIM * TT);  // 3*256*64
    unsigned short* w1b = w0b + 3 * 256 * 64;                      // 3*256*256
    unsigned short* w2b = w1b + 3 * 256 * 256;                     // 3*96*256

    // weight preconvert + transpose to [k][o][ci] bf16
    wconv_kernel<<<dim3(256), 256, 0, stream>>>(W0, W1, W2, w0b, w1b, w2b);
    // conv1: 64 -> 256, relu (fp32 in, bf16 out); 8 waves, 128 o/block
    convm<64, 256, 8, false, false><<<dim3(BB, 2, 4), 512, 0, stream>>>(
        x, w0b, b0, h0b, nullptr, nullptr, nullptr);
    // conv2: 256 -> 256, relu (bf16 in/out); 8 waves, 128 o/block
    convm<256, 256, 8, false, true><<<dim3(BB, 2, 4), 512, 0, stream>>>(
        h0b, w1b, b1, h1b, nullptr, nullptr, nullptr);
    // conv3: 256 -> 96, stats (bf16 in, fp32 mu/dd/ss out); 3 waves, 48 o/block
    convm<256, 96, 3, true, true><<<dim3(BB, 2, 4), 192, 0, stream>>>(
        h1b, w2b, b2, nullptr, mu, dd, ss);
    // banded inverse-transpose, write-bound; 4 row-bands per (b,z)
    tril_kernel<<<dim3(BB * ZDIM, 4), 64, 0, stream>>>(dd, ss, st);
}